// Round 3
// baseline (897.096 us; speedup 1.0000x reference)
//
#include <hip/hip_runtime.h>
#include <hip/hip_bf16.h>
#include <cstdint>
#include <math.h>

// Problem constants (from reference)
#define T_TOK 4096
#define E_EXP 64
#define KSEL  8
#define H_DIM 1024
#define F_DIM 512
#define C_CAP 1024

typedef __bf16 bf16x8 __attribute__((ext_vector_type(8)));
typedef __bf16 bf16x4 __attribute__((ext_vector_type(4)));
typedef float  f32x4  __attribute__((ext_vector_type(4)));

// ---------------- ws layout (bytes) ----------------
#define OFF_WT     ((size_t)0)
#define OFF_GWT    ((size_t)131072)
#define OFF_GTOK   ((size_t)393216)
#define OFF_MASKS  ((size_t)655360)
#define OFF_COUNTS ((size_t)688128)
#define OFF_XB     ((size_t)1 << 20)
#define OFF_WGT    ((size_t)9 << 20)
#define OFF_WUT    ((size_t)73 << 20)
#define OFF_HBUF   ((size_t)137 << 20)

// async global->LDS, 16B per lane. LDS dest is wave-uniform base + lane*16
// (first active lane's pointer is taken); global src is PER-LANE (gather ok).
__device__ __forceinline__ void gl16(const __bf16* g, __bf16* l)
{
    __builtin_amdgcn_global_load_lds(
        (const __attribute__((address_space(1))) void*)g,
        (__attribute__((address_space(3))) void*)l,
        16, 0, 0);
}

// ---------------- router: fp64 logits/scores (index-exactness vs np fp64 ref), top-8 ----------------
// NOTE: harness reads the whole d_out buffer as float32 and splits into chunks,
// so expert_index must be stored as FLOAT VALUES (0.0..63.0), not int32 bits.
__global__ __launch_bounds__(64) void router_kernel(
    const float* __restrict__ x, const float* __restrict__ wr,
    const float* __restrict__ bias,
    float* __restrict__ logits_out, float* __restrict__ idx_out,
    float* __restrict__ wt_buf, unsigned long long* __restrict__ masks,
    __bf16* __restrict__ xb)
{
    const int t = blockIdx.x;
    const int e = threadIdx.x;              // lane == expert
    const float4* x4 = (const float4*)(x + (size_t)t * H_DIM);
    const float4* w4 = (const float4*)(wr + (size_t)e * H_DIM);

    // fp64 accumulation: near-tie ordering must match the fp64 numpy reference
    double acc = 0.0;
    #pragma unroll 4
    for (int i = 0; i < H_DIM / 4; i++) {
        float4 a = x4[i], b = w4[i];
        acc += (double)a.x * (double)b.x + (double)a.y * (double)b.y
             + (double)a.z * (double)b.z + (double)a.w * (double)b.w;
    }
    logits_out[(size_t)t * E_EXP + e] = (float)acc;

    // cast my slice of x to bf16 (lane e covers float4 indices [4e, 4e+4))
    #pragma unroll
    for (int i2 = 0; i2 < 4; i2++) {
        float4 a = x4[e * 4 + i2];
        bf16x4 v;
        v[0] = (__bf16)a.x; v[1] = (__bf16)a.y; v[2] = (__bf16)a.z; v[3] = (__bf16)a.w;
        *(bf16x4*)(xb + (size_t)t * H_DIM + (size_t)(e * 4 + i2) * 4) = v;
    }

    const double aff = 1.0 / (1.0 + exp(-acc));   // unbiased affinity (used for weights)
    double cur = aff + (double)bias[e];           // biased selection score
    double myw = 0.0; int myi = 0;
    double wsum = 0.0;
    unsigned long long msk = 0ull;

    #pragma unroll
    for (int k = 0; k < KSEL; k++) {
        double rv = cur; int ri = e;
        // butterfly argmax, tie -> lower index (matches lax.top_k / stable descending sort)
        #pragma unroll
        for (int off = 32; off > 0; off >>= 1) {
            double ov = __shfl_xor(rv, off);
            int    oi = __shfl_xor(ri, off);
            if (ov > rv || (ov == rv && oi < ri)) { rv = ov; ri = oi; }
        }
        double wa = __shfl(aff, ri);
        wsum += wa;
        if (e == k)  { myi = ri; myw = wa; }
        if (e == ri) cur = -1e300;
        msk |= 1ull << ri;
    }
    if (e < KSEL) {
        idx_out[t * KSEL + e] = (float)myi;   // FLOAT value, see note above
        wt_buf[t * KSEL + e] = (float)(myw / wsum);
    }
    if (e == 0) masks[t] = msk;
}

// ---------------- scan: per-expert token-ordered gather lists ----------------
__global__ __launch_bounds__(64) void scan_kernel(
    const unsigned long long* __restrict__ masks,
    const float* __restrict__ idx_out, const float* __restrict__ wt_buf,
    int* __restrict__ gtok, float* __restrict__ gwt, int* __restrict__ counts)
{
    const int e = blockIdx.x;
    const int lane = threadIdx.x;
    int running = 0;
    for (int base = 0; base < T_TOK; base += 64) {
        const int t = base + lane;
        const int bit = (int)((masks[t] >> e) & 1ull);
        unsigned long long bal = __ballot(bit);
        int pre = __popcll(bal & ((1ull << lane) - 1ull));
        if (bit) {
            int pos = running + pre;
            if (pos < C_CAP) {   // capacity drop: later tokens dropped, matches cumsum order
                float w = 0.f;
                #pragma unroll
                for (int j = 0; j < KSEL; j++)
                    if ((int)idx_out[t * KSEL + j] == e) w = wt_buf[t * KSEL + j];
                gtok[e * C_CAP + pos] = t;
                gwt[e * C_CAP + pos] = w;
            }
        }
        running += __popcll(bal);
    }
    if (lane == 0) counts[e] = running < C_CAP ? running : C_CAP;
}

// ---------------- transpose + fp32->bf16 cast: in[e][R][Cc] -> out[e][Cc][R] ----------------
// 64x64 tile, float4 global reads, bf16x8 (16B) global stores.
__device__ __forceinline__ void tc_body(
    const float* __restrict__ in, __bf16* __restrict__ out, int e, int R, int Cc)
{
    const int r0 = blockIdx.y * 64;
    const int c0 = blockIdx.x * 64;
    __shared__ float tile[64][65];
    const int tid = threadIdx.x;
    const int tr  = tid >> 4;           // 0..15
    const int tc4 = (tid & 15) * 4;     // 0..60
    const float* src = in + ((size_t)e * R + r0) * Cc + c0;
    #pragma unroll
    for (int p = 0; p < 4; p++) {
        float4 v = *(const float4*)(src + (size_t)(tr + p * 16) * Cc + tc4);
        tile[tr + p * 16][tc4 + 0] = v.x;
        tile[tr + p * 16][tc4 + 1] = v.y;
        tile[tr + p * 16][tc4 + 2] = v.z;
        tile[tr + p * 16][tc4 + 3] = v.w;
    }
    __syncthreads();
    const int or8 = (tid & 7) * 8;
    __bf16* dst = out + ((size_t)e * Cc + c0) * R + r0;
    #pragma unroll
    for (int w = 0; w < 2; w++) {
        const int oc = (tid >> 3) + w * 32;
        bf16x8 v;
        #pragma unroll
        for (int j = 0; j < 8; j++) v[j] = (__bf16)tile[or8 + j][oc];
        *(bf16x8*)(dst + (size_t)oc * R + or8) = v;
    }
}

__global__ __launch_bounds__(256) void transpose_cast(
    const float* __restrict__ in, __bf16* __restrict__ out, int R, int Cc)
{
    tc_body(in, out, blockIdx.z, R, Cc);
}

// fused wg+wu transpose: one dispatch, z = 2*E (even->wg, odd->wu)
__global__ __launch_bounds__(256) void transpose_cast_dual(
    const float* __restrict__ in0, const float* __restrict__ in1,
    __bf16* __restrict__ out0, __bf16* __restrict__ out1, int R, int Cc)
{
    const int zz = blockIdx.z;
    tc_body((zz & 1) ? in1 : in0, (zz & 1) ? out1 : out0, zz >> 1, R, Cc);
}

// ---------------- GEMM tile config ----------------
#define BM  128
#define BK  32
#define BN1 64      // per-output N tile for gate/up
#define BN2 128     // N tile for down
#define LDL 32      // LINEAR LDS leading dim (bf16 elems) = 64B rows (global_load_lds needs linear dest)

// Swizzle (rule #21, both-sides involution): LDS row r stores global 16B-chunk c at
// LDS chunk c ^ ((r>>1)&3). Write side is linear (hardware); so the SOURCE chunk for
// the lane landing at (row=tid>>2, chunk=tid&3) is (tid&3)^((tid>>3)&3). Read side
// applies the same XOR. Spreads a 16-row fragment read over all 8 bank-quads (2-way = free).

// gate+up fused: h[e][c][f] = silu(g)*u, A rows gathered from xb by token id
__global__ __launch_bounds__(256) void gemm_gateup(
    const __bf16* __restrict__ xb, const __bf16* __restrict__ wgT,
    const __bf16* __restrict__ wuT, const int* __restrict__ gtok,
    const int* __restrict__ counts, __bf16* __restrict__ hbuf)
{
    const int e = blockIdx.z;
    const int count = counts[e];
    const int m0 = blockIdx.y * BM;
    if (m0 >= count) return;
    const int n0 = blockIdx.x * BN1;

    __shared__ __align__(16) __bf16 As[2][BM * LDL];    // 2 x 8 KB
    __shared__ __align__(16) __bf16 Bgs[2][BN1 * LDL];  // 2 x 4 KB
    __shared__ __align__(16) __bf16 Bus[2][BN1 * LDL];  // 2 x 4 KB

    const int tid  = threadIdx.x;
    const int lane = tid & 63;
    const int wave = tid >> 6;
    const int wm0 = (wave & 1) * 64;
    const int wn0 = (wave >> 1) * 32;
    const int q  = lane >> 4;
    const int ln = lane & 15;
    const int rq = q ^ ((ln >> 1) & 3);           // swizzled read chunk

    const int ra0 = tid >> 2, ra1 = ra0 + 64;
    const int kas = ((tid & 3) ^ ((tid >> 3) & 3)) * 8;   // swizzled source chunk

    // rows >= count load a VALID token's data (finite garbage): MFMA A-row r only
    // affects D-row r, and those rows are dead downstream -> contained.
    const int tfall = gtok[e * C_CAP];                 // count > 0 here since m0 < count
    const int tok0 = (m0 + ra0 < count) ? gtok[e * C_CAP + m0 + ra0] : tfall;
    const int tok1 = (m0 + ra1 < count) ? gtok[e * C_CAP + m0 + ra1] : tfall;
    const __bf16* ap0 = xb + (size_t)tok0 * H_DIM + kas;
    const __bf16* ap1 = xb + (size_t)tok1 * H_DIM + kas;
    const __bf16* gp = wgT + ((size_t)e * F_DIM + n0 + ra0) * H_DIM + kas;
    const __bf16* up = wuT + ((size_t)e * F_DIM + n0 + ra0) * H_DIM + kas;

    f32x4 accg[4][2] = {};
    f32x4 accu[4][2] = {};

    auto stage = [&](int b, int k0) {
        gl16(ap0 + k0, &As[b][tid * 8]);
        gl16(ap1 + k0, &As[b][2048 + tid * 8]);
        gl16(gp  + k0, &Bgs[b][tid * 8]);
        gl16(up  + k0, &Bus[b][tid * 8]);
    };
    auto compute = [&](int b) {
        bf16x8 af[4], bg[2], bu[2];
        #pragma unroll
        for (int i = 0; i < 4; i++)
            af[i] = *(const bf16x8*)(&As[b][(wm0 + i * 16 + ln) * LDL + rq * 8]);
        #pragma unroll
        for (int j = 0; j < 2; j++) {
            bg[j] = *(const bf16x8*)(&Bgs[b][(wn0 + j * 16 + ln) * LDL + rq * 8]);
            bu[j] = *(const bf16x8*)(&Bus[b][(wn0 + j * 16 + ln) * LDL + rq * 8]);
        }
        #pragma unroll
        for (int i = 0; i < 4; i++)
            #pragma unroll
            for (int j = 0; j < 2; j++) {
                accg[i][j] = __builtin_amdgcn_mfma_f32_16x16x32_bf16(af[i], bg[j], accg[i][j], 0, 0, 0);
                accu[i][j] = __builtin_amdgcn_mfma_f32_16x16x32_bf16(af[i], bu[j], accu[i][j], 0, 0, 0);
            }
    };

    // 2-phase pipeline: stage(next) issued BEFORE compute(cur); the single
    // __syncthreads' implicit vmcnt(0) drain lands AFTER compute -> HBM latency
    // overlaps ds_read+MFMA. One barrier per K-step.
    stage(0, 0);
    __syncthreads();
    int cur = 0;
    for (int t = 1; t < H_DIM / BK; t++) {
        stage(cur ^ 1, t * BK);
        compute(cur);
        __syncthreads();
        cur ^= 1;
    }
    compute(cur);

    // epilogue: h = silu(g) * u -> bf16 (rows beyond count finite-garbage, dead downstream)
    #pragma unroll
    for (int i = 0; i < 4; i++) {
        const int mb = m0 + wm0 + i * 16 + q * 4;
        #pragma unroll
        for (int j = 0; j < 2; j++) {
            const int fc = n0 + wn0 + j * 16 + ln;
            #pragma unroll
            for (int r = 0; r < 4; r++) {
                float g = accg[i][j][r];
                float u = accu[i][j][r];
                float s = g / (1.f + __expf(-g));
                hbuf[((size_t)e * C_CAP + (mb + r)) * F_DIM + fc] = (__bf16)(s * u);
            }
        }
    }
}

// down GEMM + weighted scatter-combine into y (fp32 atomics; 8 adds/elem, no conflicts in practice)
__global__ __launch_bounds__(256) void gemm_down(
    const __bf16* __restrict__ hbuf, const __bf16* __restrict__ wdT,
    const int* __restrict__ gtok, const float* __restrict__ gwt,
    const int* __restrict__ counts, float* __restrict__ y)
{
    const int e = blockIdx.z;
    const int count = counts[e];
    const int m0 = blockIdx.y * BM;
    if (m0 >= count) return;
    const int n0 = blockIdx.x * BN2;

    __shared__ __align__(16) __bf16 As[2][BM * LDL];   // 2 x 8 KB
    __shared__ __align__(16) __bf16 Bs[2][BN2 * LDL];  // 2 x 8 KB

    const int tid  = threadIdx.x;
    const int lane = tid & 63;
    const int wave = tid >> 6;
    const int wm0 = (wave & 1) * 64;
    const int wn0 = (wave >> 1) * 64;
    const int q  = lane >> 4;
    const int ln = lane & 15;
    const int rq = q ^ ((ln >> 1) & 3);

    const int ra0 = tid >> 2, ra1 = ra0 + 64;
    const int kas = ((tid & 3) ^ ((tid >> 3) & 3)) * 8;

    const __bf16* ap0 = hbuf + ((size_t)e * C_CAP + m0 + ra0) * F_DIM + kas;
    const __bf16* ap1 = hbuf + ((size_t)e * C_CAP + m0 + ra1) * F_DIM + kas;
    const __bf16* bp0 = wdT + ((size_t)e * H_DIM + n0 + ra0) * F_DIM + kas;
    const __bf16* bp1 = wdT + ((size_t)e * H_DIM + n0 + ra1) * F_DIM + kas;

    f32x4 acc[4][4] = {};

    auto stage = [&](int b, int k0) {
        gl16(ap0 + k0, &As[b][tid * 8]);
        gl16(ap1 + k0, &As[b][2048 + tid * 8]);
        gl16(bp0 + k0, &Bs[b][tid * 8]);
        gl16(bp1 + k0, &Bs[b][2048 + tid * 8]);
    };
    auto compute = [&](int b) {
        bf16x8 af[4], bb[4];
        #pragma unroll
        for (int i = 0; i < 4; i++)
            af[i] = *(const bf16x8*)(&As[b][(wm0 + i * 16 + ln) * LDL + rq * 8]);
        #pragma unroll
        for (int j = 0; j < 4; j++)
            bb[j] = *(const bf16x8*)(&Bs[b][(wn0 + j * 16 + ln) * LDL + rq * 8]);
        #pragma unroll
        for (int i = 0; i < 4; i++)
            #pragma unroll
            for (int j = 0; j < 4; j++)
                acc[i][j] = __builtin_amdgcn_mfma_f32_16x16x32_bf16(af[i], bb[j], acc[i][j], 0, 0, 0);
    };

    stage(0, 0);
    __syncthreads();
    int cur = 0;
    for (int t = 1; t < F_DIM / BK; t++) {
        stage(cur ^ 1, t * BK);
        compute(cur);
        __syncthreads();
        cur ^= 1;
    }
    compute(cur);

    #pragma unroll
    for (int i = 0; i < 4; i++) {
        const int mb = wm0 + i * 16 + q * 4;
        int tokr[4]; float wtr[4];
        #pragma unroll
        for (int r = 0; r < 4; r++) {
            const int row = m0 + mb + r;
            const bool v = row < count;
            tokr[r] = v ? gtok[e * C_CAP + row] : -1;
            wtr[r]  = v ? gwt[e * C_CAP + row] : 0.f;
        }
        #pragma unroll
        for (int j = 0; j < 4; j++) {
            const int hc = n0 + wn0 + j * 16 + ln;
            #pragma unroll
            for (int r = 0; r < 4; r++) {
                if (tokr[r] >= 0)
                    atomicAdd(&y[(size_t)tokr[r] * H_DIM + hc], acc[i][j][r] * wtr[r]);
            }
        }
    }
}

extern "C" void kernel_launch(void* const* d_in, const int* in_sizes, int n_in,
                              void* d_out, int out_size, void* d_ws, size_t ws_size,
                              hipStream_t stream)
{
    const float* x    = (const float*)d_in[0];
    const float* wr   = (const float*)d_in[1];
    const float* bias = (const float*)d_in[2];
    const float* wg   = (const float*)d_in[3];
    const float* wu   = (const float*)d_in[4];
    const float* wd   = (const float*)d_in[5];

    float* y      = (float*)d_out;
    float* logits = y + (size_t)T_TOK * H_DIM;
    float* idxo   = logits + (size_t)T_TOK * E_EXP;   // stored as float values (harness reads f32)

    char* ws = (char*)d_ws;
    float*  wt_buf = (float*)(ws + OFF_WT);
    float*  gwt    = (float*)(ws + OFF_GWT);
    int*    gtok   = (int*)(ws + OFF_GTOK);
    unsigned long long* masks = (unsigned long long*)(ws + OFF_MASKS);
    int*    counts = (int*)(ws + OFF_COUNTS);
    __bf16* xb   = (__bf16*)(ws + OFF_XB);
    __bf16* wgT  = (__bf16*)(ws + OFF_WGT);
    __bf16* wuT  = (__bf16*)(ws + OFF_WUT);
    __bf16* wdT  = wuT;                       // w_down transposed reuses w_up region after gemm1
    __bf16* hbuf = (__bf16*)(ws + OFF_HBUF);

    // y accumulated by atomics -> zero it (harness poisons d_out each call)
    hipMemsetAsync(d_out, 0, (size_t)T_TOK * H_DIM * sizeof(float), stream);

    router_kernel<<<T_TOK, 64, 0, stream>>>(x, wr, bias, logits, idxo, wt_buf, masks, xb);
    scan_kernel<<<E_EXP, 64, 0, stream>>>(masks, idxo, wt_buf, gtok, gwt, counts);

    // w_gate/w_up: [E][H][F] -> [E][F][H]   (R=H, Cc=F), fused into one dispatch
    transpose_cast_dual<<<dim3(F_DIM / 64, H_DIM / 64, 2 * E_EXP), 256, 0, stream>>>(
        wg, wu, wgT, wuT, H_DIM, F_DIM);

    gemm_gateup<<<dim3(F_DIM / BN1, C_CAP / BM, E_EXP), 256, 0, stream>>>(
        xb, wgT, wuT, gtok, counts, hbuf);

    // w_down: [E][F][H] -> [E][H][F], into wuT region (dead after gemm_gateup)
    transpose_cast<<<dim3(H_DIM / 64, F_DIM / 64, E_EXP), 256, 0, stream>>>(wd, wdT, F_DIM, H_DIM);

    gemm_down<<<dim3(H_DIM / BN2, C_CAP / BM, E_EXP), 256, 0, stream>>>(
        hbuf, wdT, gtok, gwt, counts, y);
}

// Round 4
// 858.190 us; speedup vs baseline: 1.0453x; 1.0453x over previous
//
#include <hip/hip_runtime.h>
#include <hip/hip_bf16.h>
#include <cstdint>
#include <math.h>

// Problem constants (from reference)
#define T_TOK 4096
#define E_EXP 64
#define KSEL  8
#define H_DIM 1024
#define F_DIM 512
#define C_CAP 1024

typedef __bf16 bf16x8 __attribute__((ext_vector_type(8)));
typedef __bf16 bf16x4 __attribute__((ext_vector_type(4)));
typedef float  f32x4  __attribute__((ext_vector_type(4)));

// ---------------- ws layout (bytes) ----------------
#define OFF_WT     ((size_t)0)
#define OFF_GWT    ((size_t)131072)
#define OFF_GTOK   ((size_t)393216)
#define OFF_MASKS  ((size_t)655360)
#define OFF_COUNTS ((size_t)688128)
#define OFF_POSB   ((size_t)720896)          // int[T][K] slot->pos table (128 KB), ends < 1 MiB
#define OFF_XB     ((size_t)1 << 20)
#define OFF_WGT    ((size_t)9 << 20)
#define OFF_WUT    ((size_t)73 << 20)
#define OFF_HBUF   ((size_t)137 << 20)
#define OFF_OBUF   ((size_t)201 << 20)       // bf16[E][C][H] = 128 MiB (optional, ws permitting)
#define OBUF_BYTES ((size_t)E_EXP * C_CAP * H_DIM * 2)

// async global->LDS, 16B per lane. LDS dest is wave-uniform base + lane*16
// (first active lane's pointer is taken); global src is PER-LANE (gather ok).
__device__ __forceinline__ void gl16(const __bf16* g, __bf16* l)
{
    __builtin_amdgcn_global_load_lds(
        (const __attribute__((address_space(1))) void*)g,
        (__attribute__((address_space(3))) void*)l,
        16, 0, 0);
}

// ---------------- router: fp64 logits/scores (index-exactness vs np fp64 ref), top-8 ----------------
// NOTE: harness reads the whole d_out buffer as float32 and splits into chunks,
// so expert_index must be stored as FLOAT VALUES (0.0..63.0), not int32 bits.
__global__ __launch_bounds__(64) void router_kernel(
    const float* __restrict__ x, const float* __restrict__ wr,
    const float* __restrict__ bias,
    float* __restrict__ logits_out, float* __restrict__ idx_out,
    float* __restrict__ wt_buf, unsigned long long* __restrict__ masks,
    __bf16* __restrict__ xb)
{
    const int t = blockIdx.x;
    const int e = threadIdx.x;              // lane == expert
    const float4* x4 = (const float4*)(x + (size_t)t * H_DIM);
    const float4* w4 = (const float4*)(wr + (size_t)e * H_DIM);

    // fp64 accumulation: near-tie ordering must match the fp64 numpy reference
    double acc = 0.0;
    #pragma unroll 4
    for (int i = 0; i < H_DIM / 4; i++) {
        float4 a = x4[i], b = w4[i];
        acc += (double)a.x * (double)b.x + (double)a.y * (double)b.y
             + (double)a.z * (double)b.z + (double)a.w * (double)b.w;
    }
    logits_out[(size_t)t * E_EXP + e] = (float)acc;

    // cast my slice of x to bf16 (lane e covers float4 indices [4e, 4e+4))
    #pragma unroll
    for (int i2 = 0; i2 < 4; i2++) {
        float4 a = x4[e * 4 + i2];
        bf16x4 v;
        v[0] = (__bf16)a.x; v[1] = (__bf16)a.y; v[2] = (__bf16)a.z; v[3] = (__bf16)a.w;
        *(bf16x4*)(xb + (size_t)t * H_DIM + (size_t)(e * 4 + i2) * 4) = v;
    }

    const double aff = 1.0 / (1.0 + exp(-acc));   // unbiased affinity (used for weights)
    double cur = aff + (double)bias[e];           // biased selection score
    double myw = 0.0; int myi = 0;
    double wsum = 0.0;
    unsigned long long msk = 0ull;

    #pragma unroll
    for (int k = 0; k < KSEL; k++) {
        double rv = cur; int ri = e;
        // butterfly argmax, tie -> lower index (matches lax.top_k / stable descending sort)
        #pragma unroll
        for (int off = 32; off > 0; off >>= 1) {
            double ov = __shfl_xor(rv, off);
            int    oi = __shfl_xor(ri, off);
            if (ov > rv || (ov == rv && oi < ri)) { rv = ov; ri = oi; }
        }
        double wa = __shfl(aff, ri);
        wsum += wa;
        if (e == k)  { myi = ri; myw = wa; }
        if (e == ri) cur = -1e300;
        msk |= 1ull << ri;
    }
    if (e < KSEL) {
        idx_out[t * KSEL + e] = (float)myi;   // FLOAT value, see note above
        wt_buf[t * KSEL + e] = (float)(myw / wsum);
    }
    if (e == 0) masks[t] = msk;
}

// ---------------- scan: per-expert token-ordered gather lists + (t,k)->pos table ----------------
__global__ __launch_bounds__(64) void scan_kernel(
    const unsigned long long* __restrict__ masks,
    const float* __restrict__ idx_out, const float* __restrict__ wt_buf,
    int* __restrict__ gtok, float* __restrict__ gwt, int* __restrict__ counts,
    int* __restrict__ posb)
{
    const int e = blockIdx.x;
    const int lane = threadIdx.x;
    int running = 0;
    for (int base = 0; base < T_TOK; base += 64) {
        const int t = base + lane;
        const int bit = (int)((masks[t] >> e) & 1ull);
        unsigned long long bal = __ballot(bit);
        int pre = __popcll(bal & ((1ull << lane) - 1ull));
        if (bit) {
            int j = 0; float w = 0.f;
            #pragma unroll
            for (int jj = 0; jj < KSEL; jj++)
                if ((int)idx_out[t * KSEL + jj] == e) { j = jj; w = wt_buf[t * KSEL + jj]; }
            int pos = running + pre;
            if (pos < C_CAP) {   // capacity drop: later tokens dropped, matches cumsum order
                gtok[e * C_CAP + pos] = t;
                gwt[e * C_CAP + pos] = w;
                posb[t * KSEL + j] = pos;
            } else {
                posb[t * KSEL + j] = -1;   // dropped: contributes 0 (weights stay normalized over all 8)
            }
        }
        running += __popcll(bal);
    }
    if (lane == 0) counts[e] = running < C_CAP ? running : C_CAP;
}

// ---------------- transpose + fp32->bf16 cast: in[e][R][Cc] -> out[e][Cc][R] ----------------
// 64x64 tile, float4 global reads, bf16x8 (16B) global stores.
__device__ __forceinline__ void tc_body(
    const float* __restrict__ in, __bf16* __restrict__ out, int e, int R, int Cc)
{
    const int r0 = blockIdx.y * 64;
    const int c0 = blockIdx.x * 64;
    __shared__ float tile[64][65];
    const int tid = threadIdx.x;
    const int tr  = tid >> 4;           // 0..15
    const int tc4 = (tid & 15) * 4;     // 0..60
    const float* src = in + ((size_t)e * R + r0) * Cc + c0;
    #pragma unroll
    for (int p = 0; p < 4; p++) {
        float4 v = *(const float4*)(src + (size_t)(tr + p * 16) * Cc + tc4);
        tile[tr + p * 16][tc4 + 0] = v.x;
        tile[tr + p * 16][tc4 + 1] = v.y;
        tile[tr + p * 16][tc4 + 2] = v.z;
        tile[tr + p * 16][tc4 + 3] = v.w;
    }
    __syncthreads();
    const int or8 = (tid & 7) * 8;
    __bf16* dst = out + ((size_t)e * Cc + c0) * R + r0;
    #pragma unroll
    for (int w = 0; w < 2; w++) {
        const int oc = (tid >> 3) + w * 32;
        bf16x8 v;
        #pragma unroll
        for (int j = 0; j < 8; j++) v[j] = (__bf16)tile[or8 + j][oc];
        *(bf16x8*)(dst + (size_t)oc * R + or8) = v;
    }
}

__global__ __launch_bounds__(256) void transpose_cast(
    const float* __restrict__ in, __bf16* __restrict__ out, int R, int Cc)
{
    tc_body(in, out, blockIdx.z, R, Cc);
}

// fused wg+wu transpose: one dispatch, z = 2*E (even->wg, odd->wu)
__global__ __launch_bounds__(256) void transpose_cast_dual(
    const float* __restrict__ in0, const float* __restrict__ in1,
    __bf16* __restrict__ out0, __bf16* __restrict__ out1, int R, int Cc)
{
    const int zz = blockIdx.z;
    tc_body((zz & 1) ? in1 : in0, (zz & 1) ? out1 : out0, zz >> 1, R, Cc);
}

// ---------------- GEMM tile config ----------------
#define BM  128
#define BK  32
#define BN1 64      // per-output N tile for gate/up
#define BN2 128     // N tile for down
#define LDL 32      // LINEAR LDS leading dim (bf16 elems) = 64B rows (global_load_lds needs linear dest)

// Swizzle (rule #21, both-sides involution): LDS row r stores global 16B-chunk c at
// LDS chunk c ^ ((r>>1)&3). Write side is linear (hardware); so the SOURCE chunk for
// the lane landing at (row=tid>>2, chunk=tid&3) is (tid&3)^((tid>>3)&3). Read side
// applies the same XOR. Spreads a 16-row fragment read over all 8 bank-quads (2-way = free).

// Distance-2 pipeline (T4 counted vmcnt): per K-step, only the OLDEST staged tile must
// have landed (s_waitcnt vmcnt(LOADS)) -- the newest LOADS stay in flight across the
// barrier, so HBM latency is covered by ~2 K-steps of compute instead of 0.

// gate+up fused: h[e][c][f] = silu(g)*u, A rows gathered from xb by token id
__global__ __launch_bounds__(256) void gemm_gateup(
    const __bf16* __restrict__ xb, const __bf16* __restrict__ wgT,
    const __bf16* __restrict__ wuT, const int* __restrict__ gtok,
    const int* __restrict__ counts, __bf16* __restrict__ hbuf)
{
    const int e = blockIdx.z;
    const int count = counts[e];
    const int m0 = blockIdx.y * BM;
    if (m0 >= count) return;
    const int n0 = blockIdx.x * BN1;

    __shared__ __align__(16) __bf16 As[2][BM * LDL];    // 2 x 8 KB
    __shared__ __align__(16) __bf16 Bgs[2][BN1 * LDL];  // 2 x 4 KB
    __shared__ __align__(16) __bf16 Bus[2][BN1 * LDL];  // 2 x 4 KB

    const int tid  = threadIdx.x;
    const int lane = tid & 63;
    const int wave = tid >> 6;
    const int wm0 = (wave & 1) * 64;
    const int wn0 = (wave >> 1) * 32;
    const int q  = lane >> 4;
    const int ln = lane & 15;
    const int rq = q ^ ((ln >> 1) & 3);           // swizzled read chunk

    const int ra0 = tid >> 2, ra1 = ra0 + 64;
    const int kas = ((tid & 3) ^ ((tid >> 3) & 3)) * 8;   // swizzled source chunk

    // rows >= count load a VALID token's data (finite garbage): MFMA A-row r only
    // affects D-row r, and those rows are dead downstream -> contained.
    const int tfall = gtok[e * C_CAP];                 // count > 0 here since m0 < count
    const int tok0 = (m0 + ra0 < count) ? gtok[e * C_CAP + m0 + ra0] : tfall;
    const int tok1 = (m0 + ra1 < count) ? gtok[e * C_CAP + m0 + ra1] : tfall;
    const __bf16* ap0 = xb + (size_t)tok0 * H_DIM + kas;
    const __bf16* ap1 = xb + (size_t)tok1 * H_DIM + kas;
    const __bf16* gp = wgT + ((size_t)e * F_DIM + n0 + ra0) * H_DIM + kas;
    const __bf16* up = wuT + ((size_t)e * F_DIM + n0 + ra0) * H_DIM + kas;

    f32x4 accg[4][2] = {};
    f32x4 accu[4][2] = {};

    auto stage = [&](int b, int k0) {     // 4 vmcnt-units per thread
        gl16(ap0 + k0, &As[b][tid * 8]);
        gl16(ap1 + k0, &As[b][2048 + tid * 8]);
        gl16(gp  + k0, &Bgs[b][tid * 8]);
        gl16(up  + k0, &Bus[b][tid * 8]);
    };
    auto compute = [&](int b) {
        bf16x8 af[4], bg[2], bu[2];
        #pragma unroll
        for (int i = 0; i < 4; i++)
            af[i] = *(const bf16x8*)(&As[b][(wm0 + i * 16 + ln) * LDL + rq * 8]);
        #pragma unroll
        for (int j = 0; j < 2; j++) {
            bg[j] = *(const bf16x8*)(&Bgs[b][(wn0 + j * 16 + ln) * LDL + rq * 8]);
            bu[j] = *(const bf16x8*)(&Bus[b][(wn0 + j * 16 + ln) * LDL + rq * 8]);
        }
        #pragma unroll
        for (int i = 0; i < 4; i++)
            #pragma unroll
            for (int j = 0; j < 2; j++) {
                accg[i][j] = __builtin_amdgcn_mfma_f32_16x16x32_bf16(af[i], bg[j], accg[i][j], 0, 0, 0);
                accu[i][j] = __builtin_amdgcn_mfma_f32_16x16x32_bf16(af[i], bu[j], accu[i][j], 0, 0, 0);
            }
    };

    const int NT = H_DIM / BK;   // 32
    stage(0, 0);
    stage(1, BK);
    #pragma unroll 1
    for (int t = 0; t < NT - 1; t++) {
        // own oldest 4 loads (tile t) done; tile t+1's 4 may stay in flight
        asm volatile("s_waitcnt vmcnt(4)" ::: "memory");
        __builtin_amdgcn_s_barrier();          // all waves' tile-t contributions landed
        __builtin_amdgcn_sched_barrier(0);
        compute(t & 1);
        __builtin_amdgcn_sched_barrier(0);     // keep ds_reads above the barrier
        __builtin_amdgcn_s_barrier();          // everyone done reading buf[t&1]
        __builtin_amdgcn_sched_barrier(0);
        if (t + 2 < NT) stage(t & 1, (t + 2) * BK);
    }
    asm volatile("s_waitcnt vmcnt(0)" ::: "memory");
    __builtin_amdgcn_s_barrier();
    __builtin_amdgcn_sched_barrier(0);
    compute((NT - 1) & 1);

    // epilogue: h = silu(g) * u -> bf16 (rows beyond count finite-garbage, dead downstream)
    #pragma unroll
    for (int i = 0; i < 4; i++) {
        const int mb = m0 + wm0 + i * 16 + q * 4;
        #pragma unroll
        for (int j = 0; j < 2; j++) {
            const int fc = n0 + wn0 + j * 16 + ln;
            #pragma unroll
            for (int r = 0; r < 4; r++) {
                float g = accg[i][j][r];
                float u = accu[i][j][r];
                float s = g / (1.f + __expf(-g));
                hbuf[((size_t)e * C_CAP + (mb + r)) * F_DIM + fc] = (__bf16)(s * u);
            }
        }
    }
}

// down GEMM: o[e][c][h] to obuf (plain bf16 stores) when obuf != nullptr,
// else legacy weighted atomic scatter into y.
__global__ __launch_bounds__(256) void gemm_down(
    const __bf16* __restrict__ hbuf, const __bf16* __restrict__ wdT,
    const int* __restrict__ gtok, const float* __restrict__ gwt,
    const int* __restrict__ counts, float* __restrict__ y, __bf16* __restrict__ obuf)
{
    const int e = blockIdx.z;
    const int count = counts[e];
    const int m0 = blockIdx.y * BM;
    if (m0 >= count) return;
    const int n0 = blockIdx.x * BN2;

    __shared__ __align__(16) __bf16 As[2][BM * LDL];   // 2 x 8 KB
    __shared__ __align__(16) __bf16 Bs[2][BN2 * LDL];  // 2 x 8 KB

    const int tid  = threadIdx.x;
    const int lane = tid & 63;
    const int wave = tid >> 6;
    const int wm0 = (wave & 1) * 64;
    const int wn0 = (wave >> 1) * 64;
    const int q  = lane >> 4;
    const int ln = lane & 15;
    const int rq = q ^ ((ln >> 1) & 3);

    const int ra0 = tid >> 2, ra1 = ra0 + 64;
    const int kas = ((tid & 3) ^ ((tid >> 3) & 3)) * 8;

    const __bf16* ap0 = hbuf + ((size_t)e * C_CAP + m0 + ra0) * F_DIM + kas;
    const __bf16* ap1 = hbuf + ((size_t)e * C_CAP + m0 + ra1) * F_DIM + kas;
    const __bf16* bp0 = wdT + ((size_t)e * H_DIM + n0 + ra0) * F_DIM + kas;
    const __bf16* bp1 = wdT + ((size_t)e * H_DIM + n0 + ra1) * F_DIM + kas;

    f32x4 acc[4][4] = {};

    auto stage = [&](int b, int k0) {     // 4 vmcnt-units per thread
        gl16(ap0 + k0, &As[b][tid * 8]);
        gl16(ap1 + k0, &As[b][2048 + tid * 8]);
        gl16(bp0 + k0, &Bs[b][tid * 8]);
        gl16(bp1 + k0, &Bs[b][2048 + tid * 8]);
    };
    auto compute = [&](int b) {
        bf16x8 af[4], bb[4];
        #pragma unroll
        for (int i = 0; i < 4; i++)
            af[i] = *(const bf16x8*)(&As[b][(wm0 + i * 16 + ln) * LDL + rq * 8]);
        #pragma unroll
        for (int j = 0; j < 4; j++)
            bb[j] = *(const bf16x8*)(&Bs[b][(wn0 + j * 16 + ln) * LDL + rq * 8]);
        #pragma unroll
        for (int i = 0; i < 4; i++)
            #pragma unroll
            for (int j = 0; j < 4; j++)
                acc[i][j] = __builtin_amdgcn_mfma_f32_16x16x32_bf16(af[i], bb[j], acc[i][j], 0, 0, 0);
    };

    const int NT = F_DIM / BK;   // 16
    stage(0, 0);
    stage(1, BK);
    #pragma unroll 1
    for (int t = 0; t < NT - 1; t++) {
        asm volatile("s_waitcnt vmcnt(4)" ::: "memory");
        __builtin_amdgcn_s_barrier();
        __builtin_amdgcn_sched_barrier(0);
        compute(t & 1);
        __builtin_amdgcn_sched_barrier(0);
        __builtin_amdgcn_s_barrier();
        __builtin_amdgcn_sched_barrier(0);
        if (t + 2 < NT) stage(t & 1, (t + 2) * BK);
    }
    asm volatile("s_waitcnt vmcnt(0)" ::: "memory");
    __builtin_amdgcn_s_barrier();
    __builtin_amdgcn_sched_barrier(0);
    compute((NT - 1) & 1);

    if (obuf) {
        // plain stores; rows >= count are finite garbage, never read by combine
        #pragma unroll
        for (int i = 0; i < 4; i++) {
            const int mb = m0 + wm0 + i * 16 + q * 4;
            #pragma unroll
            for (int j = 0; j < 4; j++) {
                const int hc = n0 + wn0 + j * 16 + ln;
                #pragma unroll
                for (int r = 0; r < 4; r++)
                    obuf[((size_t)e * C_CAP + (mb + r)) * H_DIM + hc] = (__bf16)acc[i][j][r];
            }
        }
    } else {
        #pragma unroll
        for (int i = 0; i < 4; i++) {
            const int mb = wm0 + i * 16 + q * 4;
            int tokr[4]; float wtr[4];
            #pragma unroll
            for (int r = 0; r < 4; r++) {
                const int row = m0 + mb + r;
                const bool v = row < count;
                tokr[r] = v ? gtok[e * C_CAP + row] : -1;
                wtr[r]  = v ? gwt[e * C_CAP + row] : 0.f;
            }
            #pragma unroll
            for (int j = 0; j < 4; j++) {
                const int hc = n0 + wn0 + j * 16 + ln;
                #pragma unroll
                for (int r = 0; r < 4; r++) {
                    if (tokr[r] >= 0)
                        atomicAdd(&y[(size_t)tokr[r] * H_DIM + hc], acc[i][j][r] * wtr[r]);
                }
            }
        }
    }
}

// combine: y[t] = sum_k wt[t,k] * o[e_k][pos_k]  (replaces 33M atomics with 64MB of reads)
__global__ __launch_bounds__(256) void combine_kernel(
    const __bf16* __restrict__ obuf, const float* __restrict__ idxo,
    const float* __restrict__ wt_buf, const int* __restrict__ posb,
    float* __restrict__ y)
{
    const int t = blockIdx.x;
    const int tid = threadIdx.x;
    const int h = tid * 4;                 // H/256 = 4 elems per thread
    float4 acc = {0.f, 0.f, 0.f, 0.f};
    #pragma unroll
    for (int k = 0; k < KSEL; k++) {
        const int p = posb[t * KSEL + k];
        if (p >= 0) {
            const int e = (int)idxo[t * KSEL + k];
            const float w = wt_buf[t * KSEL + k];
            bf16x4 v = *(const bf16x4*)(obuf + ((size_t)e * C_CAP + p) * H_DIM + h);
            acc.x += w * (float)v[0];
            acc.y += w * (float)v[1];
            acc.z += w * (float)v[2];
            acc.w += w * (float)v[3];
        }
    }
    *(float4*)(y + (size_t)t * H_DIM + h) = acc;
}

extern "C" void kernel_launch(void* const* d_in, const int* in_sizes, int n_in,
                              void* d_out, int out_size, void* d_ws, size_t ws_size,
                              hipStream_t stream)
{
    const float* x    = (const float*)d_in[0];
    const float* wr   = (const float*)d_in[1];
    const float* bias = (const float*)d_in[2];
    const float* wg   = (const float*)d_in[3];
    const float* wu   = (const float*)d_in[4];
    const float* wd   = (const float*)d_in[5];

    float* y      = (float*)d_out;
    float* logits = y + (size_t)T_TOK * H_DIM;
    float* idxo   = logits + (size_t)T_TOK * E_EXP;   // stored as float values (harness reads f32)

    char* ws = (char*)d_ws;
    float*  wt_buf = (float*)(ws + OFF_WT);
    float*  gwt    = (float*)(ws + OFF_GWT);
    int*    gtok   = (int*)(ws + OFF_GTOK);
    unsigned long long* masks = (unsigned long long*)(ws + OFF_MASKS);
    int*    counts = (int*)(ws + OFF_COUNTS);
    int*    posb   = (int*)(ws + OFF_POSB);
    __bf16* xb   = (__bf16*)(ws + OFF_XB);
    __bf16* wgT  = (__bf16*)(ws + OFF_WGT);
    __bf16* wuT  = (__bf16*)(ws + OFF_WUT);
    __bf16* wdT  = wuT;                       // w_down transposed reuses w_up region after gemm1
    __bf16* hbuf = (__bf16*)(ws + OFF_HBUF);

    const bool use_obuf = ws_size >= OFF_OBUF + OBUF_BYTES;
    __bf16* obuf = use_obuf ? (__bf16*)(ws + OFF_OBUF) : (__bf16*)nullptr;

    if (!use_obuf) {
        // y accumulated by atomics -> zero it (harness poisons d_out each call)
        hipMemsetAsync(d_out, 0, (size_t)T_TOK * H_DIM * sizeof(float), stream);
    }

    router_kernel<<<T_TOK, 64, 0, stream>>>(x, wr, bias, logits, idxo, wt_buf, masks, xb);
    scan_kernel<<<E_EXP, 64, 0, stream>>>(masks, idxo, wt_buf, gtok, gwt, counts, posb);

    // w_gate/w_up: [E][H][F] -> [E][F][H]   (R=H, Cc=F), fused into one dispatch
    transpose_cast_dual<<<dim3(F_DIM / 64, H_DIM / 64, 2 * E_EXP), 256, 0, stream>>>(
        wg, wu, wgT, wuT, H_DIM, F_DIM);

    gemm_gateup<<<dim3(F_DIM / BN1, C_CAP / BM, E_EXP), 256, 0, stream>>>(
        xb, wgT, wuT, gtok, counts, hbuf);

    // w_down: [E][F][H] -> [E][H][F], into wuT region (dead after gemm_gateup)
    transpose_cast<<<dim3(H_DIM / 64, F_DIM / 64, E_EXP), 256, 0, stream>>>(wd, wdT, F_DIM, H_DIM);

    gemm_down<<<dim3(H_DIM / BN2, C_CAP / BM, E_EXP), 256, 0, stream>>>(
        hbuf, wdT, gtok, gwt, counts, y, obuf);

    if (use_obuf) {
        combine_kernel<<<T_TOK, 256, 0, stream>>>(obuf, idxo, wt_buf, posb, y);
    }
}